// Round 13
// baseline (311.178 us; speedup 1.0000x reference)
//
#include <hip/hip_runtime.h>
#include <hip/hip_fp16.h>

#define N_NODES 100000
#define N_EDGES 3200000
#define N_FEAT  64
#define HIDDEN  20
#define N_CLASSES 10
#define BN_EPS  1e-5f
#define NPB     51            // nodes per block (10 thr/node in gather, 5 in pre1/bn)
#define NREG    391           // ceil(N_NODES/256) regions of 256 nodes
#define RCAP    10240         // staging slots per region
#define TILE    4096          // edges per partition block (16/thread)
#define NTILE   ((N_EDGES + TILE - 1) / TILE)
#define EPT     16
#define NBUCK   64            // degree buckets (width 4)
#define WSCALE  (1.0f / 32767.0f)
#define YSTRIDE 20            // halfs per y row: 40B rows -> 4.0MB table

// fp16x4 (as float2 raw) -> fp32 fma into float4 accumulator
__device__ __forceinline__ void fma4h(float4& acc, float s, float2 raw) {
    const __half2* h = (const __half2*)&raw;
    float2 a = __half22float2(h[0]);
    float2 b = __half22float2(h[1]);
    acc.x += s * a.x; acc.y += s * a.y; acc.z += s * b.x; acc.w += s * b.y;
}

// ---------------------------------------------------------------------------
// Partition (single pass): per-thread 16 edges in registers,
// LDS histogram -> bulk reservation -> ranked contiguous staging writes.
// ---------------------------------------------------------------------------
__global__ __launch_bounds__(256) void partition_kernel(const int* __restrict__ ei,
                                                        const float* __restrict__ ew,
                                                        int* __restrict__ rcur,
                                                        int2* __restrict__ staging) {
    __shared__ int hist[NREG];
    __shared__ int base[NREG];
    int tid = threadIdx.x;
    for (int r = tid; r < NREG; r += 256) hist[r] = 0;
    __syncthreads();

    int t0 = blockIdx.x * TILE;
    int2 ebuf[EPT];
    int  rbuf[EPT];
    #pragma unroll
    for (int k = 0; k < EPT; ++k) {
        int i = t0 + tid + k * 256;
        if (i < N_EDGES) {
            int src = ei[i];
            int dst = ei[N_EDGES + i];
            float w = ew[i];
            int r = dst >> 8;
            ebuf[k].x = src | ((dst & 255) << 17);
            ebuf[k].y = __float_as_int(w);
            rbuf[k] = r;
            atomicAdd(&hist[r], 1);
        } else {
            rbuf[k] = -1;
        }
    }
    __syncthreads();

    for (int r = tid; r < NREG; r += 256) {
        int c = hist[r];
        base[r] = (c > 0) ? atomicAdd(&rcur[r], c) : 0;
        hist[r] = 0;
    }
    __syncthreads();

    #pragma unroll
    for (int k = 0; k < EPT; ++k) {
        int r = rbuf[k];
        if (r >= 0) {
            int rank = atomicAdd(&hist[r], 1);
            int p = base[r] + rank;
            if (p < RCAP) staging[(size_t)r * RCAP + p] = ebuf[k];
        }
    }
}

// ---------------------------------------------------------------------------
// Scan region counts -> bb. Also terminates rowstart.
// ---------------------------------------------------------------------------
__global__ __launch_bounds__(512) void scanreg_kernel(const int* __restrict__ rcur,
                                                      int* __restrict__ bb,
                                                      int* __restrict__ rowstart) {
    __shared__ int s[512];
    int t = threadIdx.x;
    int v = (t < NREG) ? rcur[t] : 0;
    s[t] = v;
    __syncthreads();
    for (int off = 1; off < 512; off <<= 1) {
        int u = (t >= off) ? s[t - off] : 0;
        __syncthreads();
        s[t] += u;
        __syncthreads();
    }
    if (t < NREG) bb[t] = s[t] - v;
    if (t == 0) rowstart[N_NODES] = N_EDGES;
}

// ---------------------------------------------------------------------------
// Region finalize: LDS degree hist -> scan -> rowstart (+deg, +bucket hist),
// then place packed 4B edge words into the region's dst-grouped window.
// ---------------------------------------------------------------------------
__global__ __launch_bounds__(256) void region_kernel(const int* __restrict__ rcur,
                                                     const int* __restrict__ bb,
                                                     const int2* __restrict__ staging,
                                                     int* __restrict__ rowstart,
                                                     int* __restrict__ edges,
                                                     int* __restrict__ deg,
                                                     int* __restrict__ bhist) {
    __shared__ int h[256];
    __shared__ int s[256];
    __shared__ int bh[NBUCK];
    int tid = threadIdx.x;
    int r = blockIdx.x;
    int cnt = min(rcur[r], RCAP);
    const int2* sg = staging + (size_t)r * RCAP;

    h[tid] = 0;
    if (tid < NBUCK) bh[tid] = 0;
    __syncthreads();
    for (int i = tid; i < cnt; i += 256)
        atomicAdd(&h[(sg[i].x >> 17) & 255], 1);
    __syncthreads();

    int v = h[tid];
    s[tid] = v;
    __syncthreads();
    for (int off = 1; off < 256; off <<= 1) {
        int u = (tid >= off) ? s[tid - off] : 0;
        __syncthreads();
        s[tid] += u;
        __syncthreads();
    }
    int start = bb[r] + s[tid] - v;
    int node = (r << 8) + tid;
    if (node < N_NODES) {
        rowstart[node] = start;
        deg[node] = v;
        atomicAdd(&bh[min(v >> 2, NBUCK - 1)], 1);
    }
    h[tid] = start;
    __syncthreads();

    if (tid < NBUCK && bh[tid] > 0) atomicAdd(&bhist[tid], bh[tid]);

    for (int i = tid; i < cnt; i += 256) {
        int2 e = sg[i];
        int dl = (e.x >> 17) & 255;
        int wq = __float2int_rn(__int_as_float(e.y) * 32767.0f);
        wq = min(max(wq, 0), 32767);
        int pos = atomicAdd(&h[dl], 1);
        edges[pos] = (e.x & 0x1FFFF) | (wq << 17);
    }
}

// ---------------------------------------------------------------------------
// Exclusive scan of the 64 bucket counts -> bcur (placement cursors).
// ---------------------------------------------------------------------------
__global__ __launch_bounds__(64) void bscan_kernel(const int* __restrict__ bhist,
                                                   int* __restrict__ bcur) {
    __shared__ int s[NBUCK];
    int t = threadIdx.x;
    int v = bhist[t];
    s[t] = v;
    __syncthreads();
    for (int off = 1; off < NBUCK; off <<= 1) {
        int u = (t >= off) ? s[t - off] : 0;
        __syncthreads();
        s[t] += u;
        __syncthreads();
    }
    bcur[t] = s[t] - v;
}

// ---------------------------------------------------------------------------
// Degree-bucket placement: two-phase (LDS hist -> bulk reserve -> rank) so
// nodeperm is written contiguously per (block, bucket). Nodes in nodeperm
// order have monotone-similar degree -> no wave divergence in the gather.
// ---------------------------------------------------------------------------
__global__ __launch_bounds__(256) void bucket_kernel(const int* __restrict__ deg,
                                                     int* __restrict__ bcur,
                                                     int* __restrict__ nodeperm) {
    __shared__ int hist[NBUCK];
    __shared__ int base[NBUCK];
    int tid = threadIdx.x;
    if (tid < NBUCK) hist[tid] = 0;
    __syncthreads();

    int n = blockIdx.x * 256 + tid;
    int b = -1;
    if (n < N_NODES) {
        b = min(deg[n] >> 2, NBUCK - 1);
        atomicAdd(&hist[b], 1);
    }
    __syncthreads();

    if (tid < NBUCK) {
        int c = hist[tid];
        base[tid] = (c > 0) ? atomicAdd(&bcur[tid], c) : 0;
        hist[tid] = 0;
    }
    __syncthreads();

    if (b >= 0) {
        int rank = atomicAdd(&hist[b], 1);
        nodeperm[base[b] + rank] = n;
    }
}

// ---------------------------------------------------------------------------
// Layer-1 pre-transform y = x @ W1a (64->20), fp16 40B rows (4MB).
// ---------------------------------------------------------------------------
__global__ __launch_bounds__(256) void pre1_kernel(const float* __restrict__ x,
                                                   const float* __restrict__ W1,
                                                   __half* __restrict__ y) {
    __shared__ float sW[N_FEAT * HIDDEN];
    __shared__ float sx[NPB * 65];
    int tid = threadIdx.x;
    for (int i = tid; i < N_FEAT * HIDDEN; i += 256) sW[i] = W1[i];
    int base = blockIdx.x * NPB;
    int nrows = min(NPB, N_NODES - base);
    int total = nrows * N_FEAT;
    const float* xb = x + (size_t)base * N_FEAT;
    for (int i = tid; i < total; i += 256) {
        int r = i >> 6, c = i & 63;
        sx[r * 65 + c] = xb[i];
    }
    __syncthreads();

    int n_local = tid / 5;
    int q = tid - n_local * 5;
    int n = base + n_local;
    if (tid >= 255 || n >= N_NODES) return;

    float a0 = 0.f, a1 = 0.f, a2 = 0.f, a3 = 0.f;
    const float* row = &sx[n_local * 65];
    const float* wq = &sW[4 * q];
    #pragma unroll
    for (int k = 0; k < N_FEAT; ++k) {
        float xv = row[k];
        a0 += xv * wq[k * HIDDEN + 0];
        a1 += xv * wq[k * HIDDEN + 1];
        a2 += xv * wq[k * HIDDEN + 2];
        a3 += xv * wq[k * HIDDEN + 3];
    }
    float2 st;
    ((__half2*)&st)[0] = __floats2half2_rn(a0, a1);
    ((__half2*)&st)[1] = __floats2half2_rn(a2, a3);
    *(float2*)(y + (size_t)n * YSTRIDE + 4 * q) = st;
}

// ---------------------------------------------------------------------------
// Fused gather + MLP, 10 threads/node (2 groups x 5 quads), 512-thr blocks,
// degree-sorted node order via nodeperm (no wave divergence in edge loop).
// ---------------------------------------------------------------------------
template <bool STATS, bool FINAL>
__global__ __launch_bounds__(512) void gin_fused(const int* __restrict__ nodeperm,
                                                 const int* __restrict__ rowstart,
                                                 const int* __restrict__ edges,
                                                 const __half* __restrict__ y,
                                                 const float* __restrict__ b1,
                                                 const float* __restrict__ W2,
                                                 const float* __restrict__ b2,
                                                 float* __restrict__ opre,
                                                 float* __restrict__ stats,
                                                 const float* __restrict__ o1bn,
                                                 const float* __restrict__ o2bn,
                                                 const float* __restrict__ wlin,
                                                 const float* __restrict__ blin,
                                                 float* __restrict__ out) {
    __shared__ float sW2[HIDDEN * HIDDEN];
    __shared__ float sb1[HIDDEN];
    __shared__ float sb2[HIDDEN];
    __shared__ float zsh[NPB * HIDDEN];
    __shared__ float psh[NPB * HIDDEN];
    __shared__ float sstat[STATS ? 2 * HIDDEN : 1];
    __shared__ float sfin[FINAL ? (2 * NPB * HIDDEN + 3 * HIDDEN * N_CLASSES + N_CLASSES) : 1];

    int tid = threadIdx.x;
    for (int i = tid; i < HIDDEN * HIDDEN; i += 512) sW2[i] = W2[i];
    if (tid < HIDDEN) { sb1[tid] = b1[tid]; sb2[tid] = b2[tid]; }
    if (STATS) {
        if (tid < 2 * HIDDEN) sstat[tid] = 0.f;
    }
    float* osh1 = sfin;
    float* osh2 = sfin + NPB * HIDDEN;
    float* sw   = sfin + 2 * NPB * HIDDEN;
    float* sb   = sw + 3 * HIDDEN * N_CLASSES;
    if (FINAL) {
        for (int i = tid; i < 3 * HIDDEN * N_CLASSES; i += 512) sw[i] = wlin[i];
        if (tid < N_CLASSES) sb[tid] = blin[tid];
    }
    __syncthreads();

    int n_local = tid / 10;
    int sub = tid - n_local * 10;
    int q = sub % 5;
    int g = sub / 5;
    int idx = blockIdx.x * NPB + n_local;
    bool act = (tid < 510) && (idx < N_NODES);
    int n = act ? nodeperm[idx] : 0;

    const __half* ybase = y + 4 * q;

    float4 acc0 = make_float4(0.f, 0.f, 0.f, 0.f);
    float4 acc1 = acc0, acc2 = acc0, acc3 = acc0;
    if (act) {
        int s0 = rowstart[n];
        int s1 = rowstart[n + 1];
        int half = (s1 - s0 + 1) >> 1;
        int gs0 = s0 + g * half;
        int gs1 = g ? s1 : (s0 + half);
        int i = gs0;
        int eb[8];
        bool have = (i + 8 <= gs1);
        if (have) {
            #pragma unroll
            for (int k = 0; k < 8; ++k) eb[k] = edges[i + k];
        }
        while (have) {
            float2 v[8];
            #pragma unroll
            for (int k = 0; k < 8; ++k)
                v[k] = *(const float2*)(ybase + (size_t)(eb[k] & 0x1FFFF) * YSTRIDE);
            int ni = i + 8;
            bool more = (ni + 8 <= gs1);
            int fb[8];
            if (more) {
                #pragma unroll
                for (int k = 0; k < 8; ++k) fb[k] = edges[ni + k];
            } else {
                #pragma unroll
                for (int k = 0; k < 8; ++k) fb[k] = 0;
            }
            #pragma unroll
            for (int k = 0; k < 8; ++k) {
                float s = (float)((unsigned)eb[k] >> 17) * WSCALE;
                float4& a = ((k & 3) == 0) ? acc0 : ((k & 3) == 1) ? acc1
                          : ((k & 3) == 2) ? acc2 : acc3;
                fma4h(a, s, v[k]);
            }
            #pragma unroll
            for (int k = 0; k < 8; ++k) eb[k] = fb[k];
            i = ni;
            have = more;
        }
        for (; i < gs1; ++i) {
            int e = edges[i];
            float2 vv = *(const float2*)(ybase + (size_t)(e & 0x1FFFF) * YSTRIDE);
            fma4h(acc0, (float)((unsigned)e >> 17) * WSCALE, vv);
        }
    }
    acc0.x += acc1.x + acc2.x + acc3.x;
    acc0.y += acc1.y + acc2.y + acc3.y;
    acc0.z += acc1.z + acc2.z + acc3.z;
    acc0.w += acc1.w + acc2.w + acc3.w;

    // group 1 deposits partial; group 0 combines -> z in zsh
    if (act && g == 1) {
        float* pr = &psh[n_local * HIDDEN + 4 * q];
        pr[0] = acc0.x; pr[1] = acc0.y; pr[2] = acc0.z; pr[3] = acc0.w;
    }
    __syncthreads();
    if (act && g == 0) {
        const float* pr = &psh[n_local * HIDDEN + 4 * q];
        float* zr = &zsh[n_local * HIDDEN + 4 * q];
        zr[0] = fmaxf(acc0.x + pr[0] + sb1[4 * q + 0], 0.f);
        zr[1] = fmaxf(acc0.y + pr[1] + sb1[4 * q + 1], 0.f);
        zr[2] = fmaxf(acc0.z + pr[2] + sb1[4 * q + 2], 0.f);
        zr[3] = fmaxf(acc0.w + pr[3] + sb1[4 * q + 3], 0.f);
    }
    __syncthreads();

    // o quad = relu(z_row @ W2 + b2)[quad], group 0 only
    float o[4] = {0.f, 0.f, 0.f, 0.f};
    bool lead = act && (g == 0);
    if (lead) {
        o[0] = sb2[4 * q + 0]; o[1] = sb2[4 * q + 1];
        o[2] = sb2[4 * q + 2]; o[3] = sb2[4 * q + 3];
        const float* zr = &zsh[n_local * HIDDEN];
        const float* wq = &sW2[4 * q];
        #pragma unroll
        for (int k = 0; k < HIDDEN; ++k) {
            float zk = zr[k];
            o[0] += zk * wq[k * HIDDEN + 0];
            o[1] += zk * wq[k * HIDDEN + 1];
            o[2] += zk * wq[k * HIDDEN + 2];
            o[3] += zk * wq[k * HIDDEN + 3];
        }
        #pragma unroll
        for (int j = 0; j < 4; ++j) o[j] = fmaxf(o[j], 0.f);
        if (!FINAL) {
            float* wr = opre + (size_t)n * HIDDEN + 4 * q;
            *(float4*)wr = make_float4(o[0], o[1], o[2], o[3]);
        }
    }

    if (STATS) {
        if (lead) {
            #pragma unroll
            for (int j = 0; j < 4; ++j) {
                atomicAdd(&sstat[4 * q + j], o[j]);
                atomicAdd(&sstat[HIDDEN + 4 * q + j], o[j] * o[j]);
            }
        }
        __syncthreads();
        if (tid < 2 * HIDDEN) atomicAdd(&stats[tid], sstat[tid]);
    }

    if (FINAL) {
        __syncthreads();   // all z reads done; reuse zsh as o3 row store
        if (lead) {
            float* zr = &zsh[n_local * HIDDEN + 4 * q];
            zr[0] = o[0]; zr[1] = o[1]; zr[2] = o[2]; zr[3] = o[3];
            float4 v1 = *(const float4*)(o1bn + (size_t)n * HIDDEN + 4 * q);
            float4 v2 = *(const float4*)(o2bn + (size_t)n * HIDDEN + 4 * q);
            float* p1 = &osh1[n_local * HIDDEN + 4 * q];
            float* p2 = &osh2[n_local * HIDDEN + 4 * q];
            p1[0] = v1.x; p1[1] = v1.y; p1[2] = v1.z; p1[3] = v1.w;
            p2[0] = v2.x; p2[1] = v2.y; p2[2] = v2.z; p2[3] = v2.w;
        }
        __syncthreads();
        if (lead) {
            int c = 2 * q;
            float a0 = sb[c], a1 = sb[c + 1];
            const float* r1 = &osh1[n_local * HIDDEN];
            const float* r2 = &osh2[n_local * HIDDEN];
            const float* r3 = &zsh[n_local * HIDDEN];
            #pragma unroll
            for (int j = 0; j < HIDDEN; ++j) {
                float v = r1[j];
                a0 += v * sw[j * N_CLASSES + c];
                a1 += v * sw[j * N_CLASSES + c + 1];
            }
            #pragma unroll
            for (int j = 0; j < HIDDEN; ++j) {
                float v = r2[j];
                a0 += v * sw[(HIDDEN + j) * N_CLASSES + c];
                a1 += v * sw[(HIDDEN + j) * N_CLASSES + c + 1];
            }
            #pragma unroll
            for (int j = 0; j < HIDDEN; ++j) {
                float v = r3[j];
                a0 += v * sw[(2 * HIDDEN + j) * N_CLASSES + c];
                a1 += v * sw[(2 * HIDDEN + j) * N_CLASSES + c + 1];
            }
            float* wr = out + (size_t)n * N_CLASSES + c;
            wr[0] = a0; wr[1] = a1;
        }
    }
}

// ---------------------------------------------------------------------------
// BN apply + next-layer @W1 pre-transform into the fp16 40B-row y plane.
// ---------------------------------------------------------------------------
__global__ __launch_bounds__(256) void bn_fuse(const float* __restrict__ opre,
                                               const float* __restrict__ stats,
                                               const float* __restrict__ gamma,
                                               const float* __restrict__ beta,
                                               float* __restrict__ obn,
                                               const float* __restrict__ Wnext,
                                               __half* __restrict__ y) {
    __shared__ float sc[HIDDEN], sh[HIDDEN];
    __shared__ float sW[HIDDEN * HIDDEN];
    __shared__ float hsh[NPB * HIDDEN];
    int tid = threadIdx.x;
    for (int i = tid; i < HIDDEN * HIDDEN; i += 256) sW[i] = Wnext[i];
    if (tid < HIDDEN) {
        const float invN = 1.0f / N_NODES;
        float mu  = stats[tid] * invN;
        float var = stats[HIDDEN + tid] * invN - mu * mu;
        float inv = rsqrtf(var + BN_EPS);
        float s = gamma[tid] * inv;
        sc[tid] = s;
        sh[tid] = beta[tid] - mu * s;
    }
    __syncthreads();

    int n_local = tid / 5;
    int q = tid - n_local * 5;
    int n = blockIdx.x * NPB + n_local;
    bool act = (tid < 255) && (n < N_NODES);

    if (act) {
        float4 v = *(const float4*)(opre + (size_t)n * HIDDEN + 4 * q);
        float h0 = v.x * sc[4 * q + 0] + sh[4 * q + 0];
        float h1 = v.y * sc[4 * q + 1] + sh[4 * q + 1];
        float h2 = v.z * sc[4 * q + 2] + sh[4 * q + 2];
        float h3 = v.w * sc[4 * q + 3] + sh[4 * q + 3];
        *(float4*)(obn + (size_t)n * HIDDEN + 4 * q) = make_float4(h0, h1, h2, h3);
        float* hr = &hsh[n_local * HIDDEN + 4 * q];
        hr[0] = h0; hr[1] = h1; hr[2] = h2; hr[3] = h3;
    }
    __syncthreads();

    if (act) {
        float a0 = 0.f, a1 = 0.f, a2 = 0.f, a3 = 0.f;
        const float* hr = &hsh[n_local * HIDDEN];
        const float* wq = &sW[4 * q];
        #pragma unroll
        for (int k = 0; k < HIDDEN; ++k) {
            float hk = hr[k];
            a0 += hk * wq[k * HIDDEN + 0];
            a1 += hk * wq[k * HIDDEN + 1];
            a2 += hk * wq[k * HIDDEN + 2];
            a3 += hk * wq[k * HIDDEN + 3];
        }
        float2 st;
        ((__half2*)&st)[0] = __floats2half2_rn(a0, a1);
        ((__half2*)&st)[1] = __floats2half2_rn(a2, a3);
        *(float2*)(y + (size_t)n * YSTRIDE + 4 * q) = st;
    }
}

extern "C" void kernel_launch(void* const* d_in, const int* in_sizes, int n_in,
                              void* d_out, int out_size, void* d_ws, size_t ws_size,
                              hipStream_t stream) {
    const float* x   = (const float*)d_in[0];
    const int*   ei  = (const int*)d_in[1];
    const float* ew  = (const float*)d_in[2];
    const float* w1a = (const float*)d_in[3];
    const float* b1a = (const float*)d_in[4];
    const float* w2a = (const float*)d_in[5];
    const float* b2a = (const float*)d_in[6];
    const float* g1  = (const float*)d_in[7];
    const float* be1 = (const float*)d_in[8];
    const float* w1b = (const float*)d_in[9];
    const float* b1b = (const float*)d_in[10];
    const float* w2b = (const float*)d_in[11];
    const float* b2b = (const float*)d_in[12];
    const float* g2  = (const float*)d_in[13];
    const float* be2 = (const float*)d_in[14];
    const float* w1c = (const float*)d_in[15];
    const float* b1c = (const float*)d_in[16];
    const float* w2c = (const float*)d_in[17];
    const float* b2c = (const float*)d_in[18];
    const float* wlin = (const float*)d_in[19];
    const float* blin = (const float*)d_in[20];
    float* out = (float*)d_out;

    // ---- workspace layout (bytes) ----
    char* base = (char*)d_ws;
    size_t ob = 0;
    int* rcur = (int*)(base + ob);      ob += NREG * 4;
    float* st1 = (float*)(base + ob);   ob += 2 * HIDDEN * 4;
    float* st2 = (float*)(base + ob);   ob += 2 * HIDDEN * 4;
    int* bhist = (int*)(base + ob);     ob += NBUCK * 4;
    const size_t zero_bytes = ob;
    int* bcur = (int*)(base + ob);      ob += NBUCK * 4;
    int* rowstart = (int*)(base + ob);  ob += (N_NODES + 1) * 4;
    int* bb       = (int*)(base + ob);  ob += (NREG + 1) * 4;
    int* deg      = (int*)(base + ob);  ob += N_NODES * 4;
    int* nodeperm = (int*)(base + ob);  ob += N_NODES * 4;
    ob = (ob + 63) & ~(size_t)63;
    int* edges = (int*)(base + ob);     ob += (size_t)N_EDGES * 4;     // 12.8 MB
    ob = (ob + 63) & ~(size_t)63;
    // union: staging (dead after region_kernel) overlaps y/opre/obn buffers
    const size_t u0 = ob;
    int2* staging = (int2*)(base + u0);                                // 32.03 MB
    __half* y   = (__half*)(base + u0);                                // 4.0 MB
    float* opre = (float*)(base + u0 + 4000000);                       // 8 MB
    float* o1bn = (float*)(base + u0 + 12000000);                      // 8 MB
    float* o2bn = (float*)(base + u0 + 20000000);                      // 8 MB

    const int fusedBlocks = (N_NODES + NPB - 1) / NPB;

    // ---- CSR build: partition -> scanreg -> region -> bucket sort ----
    (void)hipMemsetAsync(base, 0, zero_bytes, stream);
    partition_kernel<<<NTILE, 256, 0, stream>>>(ei, ew, rcur, staging);
    scanreg_kernel<<<1, 512, 0, stream>>>(rcur, bb, rowstart);
    region_kernel<<<NREG, 256, 0, stream>>>(rcur, bb, staging, rowstart, edges, deg, bhist);
    bscan_kernel<<<1, 64, 0, stream>>>(bhist, bcur);
    bucket_kernel<<<NREG, 256, 0, stream>>>(deg, bcur, nodeperm);

    // ---- layer 1 ----
    pre1_kernel<<<fusedBlocks, 256, 0, stream>>>(x, w1a, y);
    gin_fused<true, false><<<fusedBlocks, 512, 0, stream>>>(
        nodeperm, rowstart, edges, y, b1a, w2a, b2a, opre, st1,
        o1bn, o2bn, wlin, blin, out);
    bn_fuse<<<fusedBlocks, 256, 0, stream>>>(opre, st1, g1, be1, o1bn, w1b, y);

    // ---- layer 2 ----
    gin_fused<true, false><<<fusedBlocks, 512, 0, stream>>>(
        nodeperm, rowstart, edges, y, b1b, w2b, b2b, opre, st2,
        o1bn, o2bn, wlin, blin, out);
    bn_fuse<<<fusedBlocks, 256, 0, stream>>>(opre, st2, g2, be2, o2bn, w1c, y);

    // ---- layer 3 + final linear (fused) ----
    gin_fused<false, true><<<fusedBlocks, 512, 0, stream>>>(
        nodeperm, rowstart, edges, y, b1c, w2c, b2c, opre, st1,
        o1bn, o2bn, wlin, blin, out);
}

// Round 14
// 269.757 us; speedup vs baseline: 1.1536x; 1.1536x over previous
//
#include <hip/hip_runtime.h>
#include <hip/hip_fp16.h>

#define N_NODES 100000
#define N_EDGES 3200000
#define N_FEAT  64
#define HIDDEN  20
#define N_CLASSES 10
#define BN_EPS  1e-5f
#define NPB     51            // nodes per block (10 thr/node in gather, 5 in pre1/bn)
#define NREG    391           // ceil(N_NODES/256) regions of 256 nodes
#define RCAP    10240         // staging slots per region
#define RCAP2   12288         // padded edge window per region (>= RCAP + 256*7)
#define TILE    4096          // edges per partition block (16/thread)
#define NTILE   ((N_EDGES + TILE - 1) / TILE)
#define EPT     16
#define WSCALE  (1.0f / 32767.0f)
#define YSTRIDE 20            // halfs per y row: 40B rows -> 4.0MB table

// fp16x4 (as float2 raw) -> fp32 fma into float4 accumulator
__device__ __forceinline__ void fma4h(float4& acc, float s, float2 raw) {
    const __half2* h = (const __half2*)&raw;
    float2 a = __half22float2(h[0]);
    float2 b = __half22float2(h[1]);
    acc.x += s * a.x; acc.y += s * a.y; acc.z += s * b.x; acc.w += s * b.y;
}

// ---------------------------------------------------------------------------
// Partition (single pass): per-thread 16 edges in registers,
// LDS histogram -> bulk reservation -> ranked contiguous staging writes.
// ---------------------------------------------------------------------------
__global__ __launch_bounds__(256) void partition_kernel(const int* __restrict__ ei,
                                                        const float* __restrict__ ew,
                                                        int* __restrict__ rcur,
                                                        int2* __restrict__ staging) {
    __shared__ int hist[NREG];
    __shared__ int base[NREG];
    int tid = threadIdx.x;
    for (int r = tid; r < NREG; r += 256) hist[r] = 0;
    __syncthreads();

    int t0 = blockIdx.x * TILE;
    int2 ebuf[EPT];
    int  rbuf[EPT];
    #pragma unroll
    for (int k = 0; k < EPT; ++k) {
        int i = t0 + tid + k * 256;
        if (i < N_EDGES) {
            int src = ei[i];
            int dst = ei[N_EDGES + i];
            float w = ew[i];
            int r = dst >> 8;
            ebuf[k].x = src | ((dst & 255) << 17);
            ebuf[k].y = __float_as_int(w);
            rbuf[k] = r;
            atomicAdd(&hist[r], 1);
        } else {
            rbuf[k] = -1;
        }
    }
    __syncthreads();

    for (int r = tid; r < NREG; r += 256) {
        int c = hist[r];
        base[r] = (c > 0) ? atomicAdd(&rcur[r], c) : 0;
        hist[r] = 0;
    }
    __syncthreads();

    #pragma unroll
    for (int k = 0; k < EPT; ++k) {
        int r = rbuf[k];
        if (r >= 0) {
            int rank = atomicAdd(&hist[r], 1);
            int p = base[r] + rank;
            if (p < RCAP) staging[(size_t)r * RCAP + p] = ebuf[k];
        }
    }
}

// ---------------------------------------------------------------------------
// Region finalize: LDS degree hist -> PADDED (multiple-of-8) local scan ->
// rowstart (absolute, 16B-aligned) + nbatch, place packed 4B edge words
// (src|wq<<17) into the region's private window, zero the pad slots.
// Pad word 0 => src=0, w=0 => contributes exactly 0 to the aggregation.
// ---------------------------------------------------------------------------
__global__ __launch_bounds__(256) void region_kernel(const int* __restrict__ rcur,
                                                     const int2* __restrict__ staging,
                                                     int* __restrict__ rowstart,
                                                     int* __restrict__ nbatch,
                                                     int* __restrict__ edges) {
    __shared__ int h[256];
    __shared__ int s[256];
    int tid = threadIdx.x;
    int r = blockIdx.x;
    int cnt = min(rcur[r], RCAP);
    const int2* sg = staging + (size_t)r * RCAP;

    h[tid] = 0;
    __syncthreads();
    for (int i = tid; i < cnt; i += 256)
        atomicAdd(&h[(sg[i].x >> 17) & 255], 1);
    __syncthreads();

    int v = h[tid];
    int p = (v + 7) & ~7;               // padded count (multiple of 8 words)
    s[tid] = p;
    __syncthreads();
    for (int off = 1; off < 256; off <<= 1) {
        int u = (tid >= off) ? s[tid - off] : 0;
        __syncthreads();
        s[tid] += u;
        __syncthreads();
    }
    int start = r * RCAP2 + (s[tid] - p);   // absolute padded start (8-aligned)
    int node = (r << 8) + tid;
    if (node < N_NODES) {
        rowstart[node] = start;
        nbatch[node] = p >> 3;
    }
    h[tid] = start;                      // running cursor
    __syncthreads();

    for (int i = tid; i < cnt; i += 256) {
        int2 e = sg[i];
        int dl = (e.x >> 17) & 255;
        int wq = __float2int_rn(__int_as_float(e.y) * 32767.0f);
        wq = min(max(wq, 0), 32767);
        int pos = atomicAdd(&h[dl], 1);
        edges[pos] = (e.x & 0x1FFFF) | (wq << 17);
    }
    __syncthreads();
    // zero pad slots [start+v, start+p)
    for (int j = start + v; j < start + p; ++j) edges[j] = 0;
}

// ---------------------------------------------------------------------------
// Layer-1 pre-transform y = x @ W1a (64->20), fp16 40B rows (4MB).
// ---------------------------------------------------------------------------
__global__ __launch_bounds__(256) void pre1_kernel(const float* __restrict__ x,
                                                   const float* __restrict__ W1,
                                                   __half* __restrict__ y) {
    __shared__ float sW[N_FEAT * HIDDEN];
    __shared__ float sx[NPB * 65];
    int tid = threadIdx.x;
    for (int i = tid; i < N_FEAT * HIDDEN; i += 256) sW[i] = W1[i];
    int base = blockIdx.x * NPB;
    int nrows = min(NPB, N_NODES - base);
    int total = nrows * N_FEAT;
    const float* xb = x + (size_t)base * N_FEAT;
    for (int i = tid; i < total; i += 256) {
        int r = i >> 6, c = i & 63;
        sx[r * 65 + c] = xb[i];
    }
    __syncthreads();

    int n_local = tid / 5;
    int q = tid - n_local * 5;
    int n = base + n_local;
    if (tid >= 255 || n >= N_NODES) return;

    float a0 = 0.f, a1 = 0.f, a2 = 0.f, a3 = 0.f;
    const float* row = &sx[n_local * 65];
    const float* wq = &sW[4 * q];
    #pragma unroll
    for (int k = 0; k < N_FEAT; ++k) {
        float xv = row[k];
        a0 += xv * wq[k * HIDDEN + 0];
        a1 += xv * wq[k * HIDDEN + 1];
        a2 += xv * wq[k * HIDDEN + 2];
        a3 += xv * wq[k * HIDDEN + 3];
    }
    float2 st;
    ((__half2*)&st)[0] = __floats2half2_rn(a0, a1);
    ((__half2*)&st)[1] = __floats2half2_rn(a2, a3);
    *(float2*)(y + (size_t)n * YSTRIDE + 4 * q) = st;
}

// ---------------------------------------------------------------------------
// Fused gather + MLP, 10 threads/node (2 groups x 5 quads), 512-thr blocks.
// Edge segments padded to multiples of 8 and 16B-aligned: each 8-edge batch
// is TWO dwordx4 loads (was eight dword loads) and there is NO tail loop.
// ---------------------------------------------------------------------------
template <bool STATS, bool FINAL>
__global__ __launch_bounds__(512) void gin_fused(const int* __restrict__ rowstart,
                                                 const int* __restrict__ nbatch,
                                                 const int* __restrict__ edges,
                                                 const __half* __restrict__ y,
                                                 const float* __restrict__ b1,
                                                 const float* __restrict__ W2,
                                                 const float* __restrict__ b2,
                                                 float* __restrict__ opre,
                                                 float* __restrict__ stats,
                                                 const float* __restrict__ o1bn,
                                                 const float* __restrict__ o2bn,
                                                 const float* __restrict__ wlin,
                                                 const float* __restrict__ blin,
                                                 float* __restrict__ out) {
    __shared__ float sW2[HIDDEN * HIDDEN];
    __shared__ float sb1[HIDDEN];
    __shared__ float sb2[HIDDEN];
    __shared__ float zsh[NPB * HIDDEN];
    __shared__ float psh[NPB * HIDDEN];
    __shared__ float sstat[STATS ? 2 * HIDDEN : 1];
    __shared__ float sfin[FINAL ? (2 * NPB * HIDDEN + 3 * HIDDEN * N_CLASSES + N_CLASSES) : 1];

    int tid = threadIdx.x;
    for (int i = tid; i < HIDDEN * HIDDEN; i += 512) sW2[i] = W2[i];
    if (tid < HIDDEN) { sb1[tid] = b1[tid]; sb2[tid] = b2[tid]; }
    if (STATS) {
        if (tid < 2 * HIDDEN) sstat[tid] = 0.f;
    }
    float* osh1 = sfin;
    float* osh2 = sfin + NPB * HIDDEN;
    float* sw   = sfin + 2 * NPB * HIDDEN;
    float* sb   = sw + 3 * HIDDEN * N_CLASSES;
    if (FINAL) {
        for (int i = tid; i < 3 * HIDDEN * N_CLASSES; i += 512) sw[i] = wlin[i];
        if (tid < N_CLASSES) sb[tid] = blin[tid];
    }
    __syncthreads();

    int n_local = tid / 10;
    int sub = tid - n_local * 10;
    int q = sub % 5;
    int g = sub / 5;
    int n = blockIdx.x * NPB + n_local;
    bool act = (tid < 510) && (n < N_NODES);

    const __half* ybase = y + 4 * q;

    float4 acc0 = make_float4(0.f, 0.f, 0.f, 0.f);
    float4 acc1 = acc0, acc2 = acc0, acc3 = acc0;
    if (act) {
        int s0 = rowstart[n];
        int nb = nbatch[n];
        int bh = (nb + 1) >> 1;
        int b0 = g ? bh : 0;
        int b1 = g ? nb : bh;
        for (int b = b0; b < b1; ++b) {
            const int* ep = edges + s0 + b * 8;
            int4 ea = *(const int4*)ep;
            int4 eb = *(const int4*)(ep + 4);
            float2 v0 = *(const float2*)(ybase + (size_t)(ea.x & 0x1FFFF) * YSTRIDE);
            float2 v1 = *(const float2*)(ybase + (size_t)(ea.y & 0x1FFFF) * YSTRIDE);
            float2 v2 = *(const float2*)(ybase + (size_t)(ea.z & 0x1FFFF) * YSTRIDE);
            float2 v3 = *(const float2*)(ybase + (size_t)(ea.w & 0x1FFFF) * YSTRIDE);
            float2 v4 = *(const float2*)(ybase + (size_t)(eb.x & 0x1FFFF) * YSTRIDE);
            float2 v5 = *(const float2*)(ybase + (size_t)(eb.y & 0x1FFFF) * YSTRIDE);
            float2 v6 = *(const float2*)(ybase + (size_t)(eb.z & 0x1FFFF) * YSTRIDE);
            float2 v7 = *(const float2*)(ybase + (size_t)(eb.w & 0x1FFFF) * YSTRIDE);
            fma4h(acc0, (float)((unsigned)ea.x >> 17) * WSCALE, v0);
            fma4h(acc1, (float)((unsigned)ea.y >> 17) * WSCALE, v1);
            fma4h(acc2, (float)((unsigned)ea.z >> 17) * WSCALE, v2);
            fma4h(acc3, (float)((unsigned)ea.w >> 17) * WSCALE, v3);
            fma4h(acc0, (float)((unsigned)eb.x >> 17) * WSCALE, v4);
            fma4h(acc1, (float)((unsigned)eb.y >> 17) * WSCALE, v5);
            fma4h(acc2, (float)((unsigned)eb.z >> 17) * WSCALE, v6);
            fma4h(acc3, (float)((unsigned)eb.w >> 17) * WSCALE, v7);
        }
    }
    acc0.x += acc1.x + acc2.x + acc3.x;
    acc0.y += acc1.y + acc2.y + acc3.y;
    acc0.z += acc1.z + acc2.z + acc3.z;
    acc0.w += acc1.w + acc2.w + acc3.w;

    // group 1 deposits partial; group 0 combines -> z in zsh
    if (act && g == 1) {
        float* pr = &psh[n_local * HIDDEN + 4 * q];
        pr[0] = acc0.x; pr[1] = acc0.y; pr[2] = acc0.z; pr[3] = acc0.w;
    }
    __syncthreads();
    if (act && g == 0) {
        const float* pr = &psh[n_local * HIDDEN + 4 * q];
        float* zr = &zsh[n_local * HIDDEN + 4 * q];
        zr[0] = fmaxf(acc0.x + pr[0] + sb1[4 * q + 0], 0.f);
        zr[1] = fmaxf(acc0.y + pr[1] + sb1[4 * q + 1], 0.f);
        zr[2] = fmaxf(acc0.z + pr[2] + sb1[4 * q + 2], 0.f);
        zr[3] = fmaxf(acc0.w + pr[3] + sb1[4 * q + 3], 0.f);
    }
    __syncthreads();

    // o quad = relu(z_row @ W2 + b2)[quad], group 0 only
    float o[4] = {0.f, 0.f, 0.f, 0.f};
    bool lead = act && (g == 0);
    if (lead) {
        o[0] = sb2[4 * q + 0]; o[1] = sb2[4 * q + 1];
        o[2] = sb2[4 * q + 2]; o[3] = sb2[4 * q + 3];
        const float* zr = &zsh[n_local * HIDDEN];
        const float* wq = &sW2[4 * q];
        #pragma unroll
        for (int k = 0; k < HIDDEN; ++k) {
            float zk = zr[k];
            o[0] += zk * wq[k * HIDDEN + 0];
            o[1] += zk * wq[k * HIDDEN + 1];
            o[2] += zk * wq[k * HIDDEN + 2];
            o[3] += zk * wq[k * HIDDEN + 3];
        }
        #pragma unroll
        for (int j = 0; j < 4; ++j) o[j] = fmaxf(o[j], 0.f);
        if (!FINAL) {
            float* wr = opre + (size_t)n * HIDDEN + 4 * q;
            *(float4*)wr = make_float4(o[0], o[1], o[2], o[3]);
        }
    }

    if (STATS) {
        if (lead) {
            #pragma unroll
            for (int j = 0; j < 4; ++j) {
                atomicAdd(&sstat[4 * q + j], o[j]);
                atomicAdd(&sstat[HIDDEN + 4 * q + j], o[j] * o[j]);
            }
        }
        __syncthreads();
        if (tid < 2 * HIDDEN) atomicAdd(&stats[tid], sstat[tid]);
    }

    if (FINAL) {
        __syncthreads();   // all z reads done; reuse zsh as o3 row store
        if (lead) {
            float* zr = &zsh[n_local * HIDDEN + 4 * q];
            zr[0] = o[0]; zr[1] = o[1]; zr[2] = o[2]; zr[3] = o[3];
            float4 v1 = *(const float4*)(o1bn + (size_t)n * HIDDEN + 4 * q);
            float4 v2 = *(const float4*)(o2bn + (size_t)n * HIDDEN + 4 * q);
            float* p1 = &osh1[n_local * HIDDEN + 4 * q];
            float* p2 = &osh2[n_local * HIDDEN + 4 * q];
            p1[0] = v1.x; p1[1] = v1.y; p1[2] = v1.z; p1[3] = v1.w;
            p2[0] = v2.x; p2[1] = v2.y; p2[2] = v2.z; p2[3] = v2.w;
        }
        __syncthreads();
        if (lead) {
            int c = 2 * q;
            float a0 = sb[c], a1 = sb[c + 1];
            const float* r1 = &osh1[n_local * HIDDEN];
            const float* r2 = &osh2[n_local * HIDDEN];
            const float* r3 = &zsh[n_local * HIDDEN];
            #pragma unroll
            for (int j = 0; j < HIDDEN; ++j) {
                float v = r1[j];
                a0 += v * sw[j * N_CLASSES + c];
                a1 += v * sw[j * N_CLASSES + c + 1];
            }
            #pragma unroll
            for (int j = 0; j < HIDDEN; ++j) {
                float v = r2[j];
                a0 += v * sw[(HIDDEN + j) * N_CLASSES + c];
                a1 += v * sw[(HIDDEN + j) * N_CLASSES + c + 1];
            }
            #pragma unroll
            for (int j = 0; j < HIDDEN; ++j) {
                float v = r3[j];
                a0 += v * sw[(2 * HIDDEN + j) * N_CLASSES + c];
                a1 += v * sw[(2 * HIDDEN + j) * N_CLASSES + c + 1];
            }
            float* wr = out + (size_t)n * N_CLASSES + c;
            wr[0] = a0; wr[1] = a1;
        }
    }
}

// ---------------------------------------------------------------------------
// BN apply + next-layer @W1 pre-transform into the fp16 40B-row y plane.
// ---------------------------------------------------------------------------
__global__ __launch_bounds__(256) void bn_fuse(const float* __restrict__ opre,
                                               const float* __restrict__ stats,
                                               const float* __restrict__ gamma,
                                               const float* __restrict__ beta,
                                               float* __restrict__ obn,
                                               const float* __restrict__ Wnext,
                                               __half* __restrict__ y) {
    __shared__ float sc[HIDDEN], sh[HIDDEN];
    __shared__ float sW[HIDDEN * HIDDEN];
    __shared__ float hsh[NPB * HIDDEN];
    int tid = threadIdx.x;
    for (int i = tid; i < HIDDEN * HIDDEN; i += 256) sW[i] = Wnext[i];
    if (tid < HIDDEN) {
        const float invN = 1.0f / N_NODES;
        float mu  = stats[tid] * invN;
        float var = stats[HIDDEN + tid] * invN - mu * mu;
        float inv = rsqrtf(var + BN_EPS);
        float s = gamma[tid] * inv;
        sc[tid] = s;
        sh[tid] = beta[tid] - mu * s;
    }
    __syncthreads();

    int n_local = tid / 5;
    int q = tid - n_local * 5;
    int n = blockIdx.x * NPB + n_local;
    bool act = (tid < 255) && (n < N_NODES);

    if (act) {
        float4 v = *(const float4*)(opre + (size_t)n * HIDDEN + 4 * q);
        float h0 = v.x * sc[4 * q + 0] + sh[4 * q + 0];
        float h1 = v.y * sc[4 * q + 1] + sh[4 * q + 1];
        float h2 = v.z * sc[4 * q + 2] + sh[4 * q + 2];
        float h3 = v.w * sc[4 * q + 3] + sh[4 * q + 3];
        *(float4*)(obn + (size_t)n * HIDDEN + 4 * q) = make_float4(h0, h1, h2, h3);
        float* hr = &hsh[n_local * HIDDEN + 4 * q];
        hr[0] = h0; hr[1] = h1; hr[2] = h2; hr[3] = h3;
    }
    __syncthreads();

    if (act) {
        float a0 = 0.f, a1 = 0.f, a2 = 0.f, a3 = 0.f;
        const float* hr = &hsh[n_local * HIDDEN];
        const float* wq = &sW[4 * q];
        #pragma unroll
        for (int k = 0; k < HIDDEN; ++k) {
            float hk = hr[k];
            a0 += hk * wq[k * HIDDEN + 0];
            a1 += hk * wq[k * HIDDEN + 1];
            a2 += hk * wq[k * HIDDEN + 2];
            a3 += hk * wq[k * HIDDEN + 3];
        }
        float2 st;
        ((__half2*)&st)[0] = __floats2half2_rn(a0, a1);
        ((__half2*)&st)[1] = __floats2half2_rn(a2, a3);
        *(float2*)(y + (size_t)n * YSTRIDE + 4 * q) = st;
    }
}

extern "C" void kernel_launch(void* const* d_in, const int* in_sizes, int n_in,
                              void* d_out, int out_size, void* d_ws, size_t ws_size,
                              hipStream_t stream) {
    const float* x   = (const float*)d_in[0];
    const int*   ei  = (const int*)d_in[1];
    const float* ew  = (const float*)d_in[2];
    const float* w1a = (const float*)d_in[3];
    const float* b1a = (const float*)d_in[4];
    const float* w2a = (const float*)d_in[5];
    const float* b2a = (const float*)d_in[6];
    const float* g1  = (const float*)d_in[7];
    const float* be1 = (const float*)d_in[8];
    const float* w1b = (const float*)d_in[9];
    const float* b1b = (const float*)d_in[10];
    const float* w2b = (const float*)d_in[11];
    const float* b2b = (const float*)d_in[12];
    const float* g2  = (const float*)d_in[13];
    const float* be2 = (const float*)d_in[14];
    const float* w1c = (const float*)d_in[15];
    const float* b1c = (const float*)d_in[16];
    const float* w2c = (const float*)d_in[17];
    const float* b2c = (const float*)d_in[18];
    const float* wlin = (const float*)d_in[19];
    const float* blin = (const float*)d_in[20];
    float* out = (float*)d_out;

    // ---- workspace layout (bytes) ----
    char* base = (char*)d_ws;
    size_t ob = 0;
    int* rcur = (int*)(base + ob);      ob += NREG * 4;
    float* st1 = (float*)(base + ob);   ob += 2 * HIDDEN * 4;
    float* st2 = (float*)(base + ob);   ob += 2 * HIDDEN * 4;
    const size_t zero_bytes = ob;
    int* rowstart = (int*)(base + ob);  ob += N_NODES * 4;
    int* nbatch   = (int*)(base + ob);  ob += N_NODES * 4;
    ob = (ob + 63) & ~(size_t)63;
    int* edges = (int*)(base + ob);     ob += (size_t)NREG * RCAP2 * 4;  // 19.2 MB
    ob = (ob + 63) & ~(size_t)63;
    // union: staging (dead after region_kernel) overlaps y/opre/obn buffers
    const size_t u0 = ob;
    int2* staging = (int2*)(base + u0);                                // 32.03 MB
    __half* y   = (__half*)(base + u0);                                // 4.0 MB
    float* opre = (float*)(base + u0 + 4000000);                       // 8 MB
    float* o1bn = (float*)(base + u0 + 12000000);                      // 8 MB
    float* o2bn = (float*)(base + u0 + 20000000);                      // 8 MB

    const int fusedBlocks = (N_NODES + NPB - 1) / NPB;

    // ---- CSR build: partition -> region finalize (per-region windows) ----
    (void)hipMemsetAsync(base, 0, zero_bytes, stream);
    partition_kernel<<<NTILE, 256, 0, stream>>>(ei, ew, rcur, staging);
    region_kernel<<<NREG, 256, 0, stream>>>(rcur, staging, rowstart, nbatch, edges);

    // ---- layer 1 ----
    pre1_kernel<<<fusedBlocks, 256, 0, stream>>>(x, w1a, y);
    gin_fused<true, false><<<fusedBlocks, 512, 0, stream>>>(
        rowstart, nbatch, edges, y, b1a, w2a, b2a, opre, st1,
        o1bn, o2bn, wlin, blin, out);
    bn_fuse<<<fusedBlocks, 256, 0, stream>>>(opre, st1, g1, be1, o1bn, w1b, y);

    // ---- layer 2 ----
    gin_fused<true, false><<<fusedBlocks, 512, 0, stream>>>(
        rowstart, nbatch, edges, y, b1b, w2b, b2b, opre, st2,
        o1bn, o2bn, wlin, blin, out);
    bn_fuse<<<fusedBlocks, 256, 0, stream>>>(opre, st2, g2, be2, o2bn, w1c, y);

    // ---- layer 3 + final linear (fused) ----
    gin_fused<false, true><<<fusedBlocks, 512, 0, stream>>>(
        rowstart, nbatch, edges, y, b1c, w2c, b2c, opre, st1,
        o1bn, o2bn, wlin, blin, out);
}